// Round 1
// baseline (608.451 us; speedup 1.0000x reference)
//
#include <hip/hip_runtime.h>

typedef unsigned short ushort_t;
typedef __attribute__((ext_vector_type(8))) short short8;
typedef __attribute__((ext_vector_type(4))) float f32x4;
typedef __attribute__((ext_vector_type(4))) unsigned int u32x4;

// ---------- helpers ----------

__device__ __forceinline__ ushort_t f2bf(float f) {
    unsigned u = __builtin_bit_cast(unsigned, f);
    u += 0x7fffu + ((u >> 16) & 1u);   // round-to-nearest-even
    return (ushort_t)(u >> 16);
}

// packed fp32x2 -> bf16x2 (RNE), low half = a  (guide T12/m240: no builtin, use asm)
__device__ __forceinline__ unsigned pkbf(float a, float b) {
    unsigned r;
    asm("v_cvt_pk_bf16_f32 %0, %1, %2" : "=v"(r) : "v"(a), "v"(b));
    return r;
}

__device__ __forceinline__ float tanh_fast(float x) {
    float e = __expf(2.0f * x);
    float r = __builtin_amdgcn_rcpf(e + 1.0f);
    return __builtin_fmaf(-2.0f, r, 1.0f);
}

__device__ __forceinline__ void gld16(const ushort_t* g, ushort_t* lds) {
    __builtin_amdgcn_global_load_lds(
        (const __attribute__((address_space(1))) unsigned int*)g,
        (__attribute__((address_space(3))) unsigned int*)lds, 16, 0, 0);
}

// ---------- K_prep: Wenc fp32->bf16 + zero scores (blocks 0..255)
//                    dproj = dh@Wdec^T + bdec + benc  (blocks 256..8447)

__global__ __launch_bounds__(256) void k_prep(const float* __restrict__ Wenc,
                                              const float* __restrict__ dh,
                                              const float* __restrict__ Wd,
                                              const float* __restrict__ bd,
                                              const float* __restrict__ be,
                                              ushort_t* __restrict__ wencB,
                                              float* __restrict__ dproj,
                                              float4* __restrict__ scores4) {
    const int bx = blockIdx.x;
    const int t = threadIdx.x;
    if (bx < 256) {
        int idx = bx * 256 + t;                      // 0..65535
#pragma unroll
        for (int r = 0; r < 4; ++r) {                // 262144 float4 of Wenc
            int i = idx + r * 65536;
            float4 v = ((const float4*)Wenc)[i];
            ushort4 o;
            o.x = f2bf(v.x); o.y = f2bf(v.y); o.z = f2bf(v.z); o.w = f2bf(v.w);
            ((ushort4*)wencB)[i] = o;
        }
        if (idx < 16384) scores4[idx] = (float4){0.f, 0.f, 0.f, 0.f};
    } else {
        int wid = (bx - 256) * 4 + (t >> 6);         // 0..32767
        int lane = t & 63;
        int a = wid & 1023, b = wid >> 10;
        const float4* x = (const float4*)(dh + (size_t)b * 1024);
        const float4* wrow = (const float4*)(Wd + (size_t)a * 1024);
        float s = 0.f;
#pragma unroll
        for (int it = 0; it < 4; ++it) {
            int c = it * 64 + lane;
            float4 xv = x[c], wv = wrow[c];
            s += xv.x * wv.x + xv.y * wv.y + xv.z * wv.z + xv.w * wv.w;
        }
#pragma unroll
        for (int o = 1; o < 64; o <<= 1) s += __shfl_xor(s, o, 64);
        if (lane == 0) dproj[b * 1024 + a] = s + bd[a] + be[a];
    }
}

// ---------- K2: fused cvt + GEMM + tanh + W_v reduction -> scores ----------
// A read as fp32 from enc, converted in-reg (v_cvt_pk_bf16_f32), ds_write_b128
// with XOR swizzle on the WRITE address (global reads stay linear).
// B via global_load_lds from pre-converted bf16 Wenc (pre-swizzled source).
// MFMA core / LDS mapping identical to the verified 550us kernel.

__global__ __launch_bounds__(256, 2) void k_gemm_scores(const float* __restrict__ A,
                                                        const ushort_t* __restrict__ Bm,
                                                        const float* __restrict__ dproj,
                                                        const float* __restrict__ Wv,
                                                        float* __restrict__ scores) {
    __shared__ __align__(16) ushort_t At[256 * 64];  // 32 KB
    __shared__ __align__(16) ushort_t Bt[128 * 64];  // 16 KB

    const int tid = threadIdx.x;
    const int lane = tid & 63;
    const int w = tid >> 6;            // wave 0..3
    const int wm = w >> 1, wn = w & 1; // waves: 2 (M) x 2 (N); wave tile 128x64

    // XCD swizzle: blk&7 ~ XCD; the 8 N-sharers of an A-tile land on one XCD
    const int blk = blockIdx.x;        // 0..2047
    const int q2 = blk >> 3;           // 0..255
    const int blkN = q2 & 7;           // 0..7
    const int blkM = (blk & 7) + ((q2 >> 3) << 3);  // 0..255
    const long long arow0 = (long long)blkM * 256;
    const int brow0 = blkN * 128;

    const int sr = lane >> 3;          // row within 8-row staging chunk
    const int sgrp = lane & 7;         // 16B slot within row
    const int c8s = sgrp ^ sr;         // XOR-swizzled source col-group (B path)

    const int q = lane >> 4;           // quad
    const int ml = lane & 15;

    // A: linear fp32 source; each lane owns 8 consecutive floats (2 float4)
    const float4* ga = (const float4*)(A + (size_t)(arow0 + w * 64 + sr) * 1024) + sgrp * 2;
    // B: pre-swizzled bf16 source for linear global_load_lds destination
    const ushort_t* gb = Bm + (size_t)(brow0 + w * 32 + sr) * 1024 + c8s * 8;
    // A LDS write slot: XOR swizzle applied on the write address instead
    const int wls = sr * 64 + (c8s << 3);   // ushort units within 8-row chunk

    f32x4 acc[8][4];
#pragma unroll
    for (int i = 0; i < 8; ++i)
#pragma unroll
        for (int jj = 0; jj < 4; ++jj) acc[i][jj] = (f32x4){0.f, 0.f, 0.f, 0.f};

    for (int k0 = 0; k0 < 1024; k0 += 64) {
        // first 4 A-chunks: issue global loads before the barrier (global-only, safe)
        float4 p0[4], p1[4];
#pragma unroll
        for (int j = 0; j < 4; ++j) { p0[j] = ga[j * 2048]; p1[j] = ga[j * 2048 + 1]; }
        __syncthreads();   // previous compute done before overwriting LDS
#pragma unroll
        for (int j = 0; j < 4; ++j)                   // B: 32 rows per wave, DMA
            gld16(gb + j * 8192, &Bt[(w * 4 + j) * 512]);
#pragma unroll
        for (int j = 0; j < 4; ++j) {                 // A chunks 0..3: cvt + write
            u32x4 o;
            o.x = pkbf(p0[j].x, p0[j].y); o.y = pkbf(p0[j].z, p0[j].w);
            o.z = pkbf(p1[j].x, p1[j].y); o.w = pkbf(p1[j].z, p1[j].w);
            *(u32x4*)&At[(w * 8 + j) * 512 + wls] = o;
        }
#pragma unroll
        for (int j = 4; j < 8; ++j) {                 // A chunks 4..7: load+cvt+write
            float4 v0 = ga[j * 2048], v1 = ga[j * 2048 + 1];
            u32x4 o;
            o.x = pkbf(v0.x, v0.y); o.y = pkbf(v0.z, v0.w);
            o.z = pkbf(v1.x, v1.y); o.w = pkbf(v1.z, v1.w);
            *(u32x4*)&At[(w * 8 + j) * 512 + wls] = o;
        }
        ga += 16; gb += 64;
        __builtin_amdgcn_s_waitcnt(0);  // drain vmcnt (B DMA) + lgkm before barrier
        __syncthreads();

#pragma unroll
        for (int kk = 0; kk < 2; ++kk) {  // two k-steps of 32
            const int kb = kk * 4;
            const int slot = (kb + q) ^ (ml & 7);     // same for A and B frags
            short8 af[8], bfr[4];
#pragma unroll
            for (int i = 0; i < 8; ++i) {
                int row = wm * 128 + i * 16 + ml;
                af[i] = *(const short8*)&At[row * 64 + slot * 8];
            }
#pragma unroll
            for (int jj = 0; jj < 4; ++jj) {
                int col = wn * 64 + jj * 16 + ml;
                bfr[jj] = *(const short8*)&Bt[col * 64 + slot * 8];
            }
#pragma unroll
            for (int i = 0; i < 8; ++i)
#pragma unroll
                for (int jj = 0; jj < 4; ++jj)
                    acc[i][jj] = __builtin_amdgcn_mfma_f32_16x16x32_bf16(
                        af[i], bfr[jj], acc[i][jj], 0, 0, 0);
        }
    }

    // epilogue: scores[m] += sum_a Wv[a]*tanh(acc + dproj[b,a]) over 128 cols
    const int bb = blkM >> 3;  // 8 M-blocks (256 rows) per batch (2048 rows)
    float dp[4], wv[4];
#pragma unroll
    for (int jj = 0; jj < 4; ++jj) {
        int a = blkN * 128 + wn * 64 + jj * 16 + ml;
        dp[jj] = dproj[bb * 1024 + a];
        wv[jj] = Wv[a];
    }
#pragma unroll
    for (int i = 0; i < 8; ++i) {
        float rs[4] = {0.f, 0.f, 0.f, 0.f};
#pragma unroll
        for (int jj = 0; jj < 4; ++jj) {
            f32x4 v = acc[i][jj];
            rs[0] += wv[jj] * tanh_fast(v.x + dp[jj]);
            rs[1] += wv[jj] * tanh_fast(v.y + dp[jj]);
            rs[2] += wv[jj] * tanh_fast(v.z + dp[jj]);
            rs[3] += wv[jj] * tanh_fast(v.w + dp[jj]);
        }
#pragma unroll
        for (int r = 0; r < 4; ++r)
#pragma unroll
            for (int o = 1; o < 16; o <<= 1) rs[r] += __shfl_xor(rs[r], o, 64);
        if (ml == 0) {
            long long m0 = arow0 + wm * 128 + i * 16 + q * 4;
            atomicAdd(&scores[m0 + 0], rs[0]);
            atomicAdd(&scores[m0 + 1], rs[1]);
            atomicAdd(&scores[m0 + 2], rs[2]);
            atomicAdd(&scores[m0 + 3], rs[3]);
        }
    }
}

// ---------- K3: softmax -> alpha (context now written directly by K4) ----------

__global__ __launch_bounds__(256) void k_softmax(const float* __restrict__ scores,
                                                 float* __restrict__ alpha) {
    const int b = blockIdx.x, t = threadIdx.x;
    const int lane = t & 63, w = t >> 6;
    __shared__ float red[4];
    float v[8];
#pragma unroll
    for (int j = 0; j < 8; ++j) v[j] = scores[b * 2048 + j * 256 + t];
    float mx = v[0];
#pragma unroll
    for (int j = 1; j < 8; ++j) mx = fmaxf(mx, v[j]);
#pragma unroll
    for (int o = 1; o < 64; o <<= 1) mx = fmaxf(mx, __shfl_xor(mx, o, 64));
    if (lane == 0) red[w] = mx;
    __syncthreads();
    mx = fmaxf(fmaxf(red[0], red[1]), fmaxf(red[2], red[3]));
    float s = 0.f;
#pragma unroll
    for (int j = 0; j < 8; ++j) { v[j] = __expf(v[j] - mx); s += v[j]; }
#pragma unroll
    for (int o = 1; o < 64; o <<= 1) s += __shfl_xor(s, o, 64);
    __syncthreads();
    if (lane == 0) red[w] = s;
    __syncthreads();
    s = red[0] + red[1] + red[2] + red[3];
    float inv = 1.0f / s;
#pragma unroll
    for (int j = 0; j < 8; ++j) alpha[b * 2048 + j * 256 + t] = v[j] * inv;
}

// ---------- K4: context[b,e] = sum_s alpha[b,s]*enc[b,s,e] (fp32, no atomics) ----

__global__ __launch_bounds__(512) void k_context(const float* __restrict__ enc,
                                                 const float* __restrict__ alpha,
                                                 float* __restrict__ out) {
    const int b = blockIdx.x, ec = blockIdx.y;   // (32, 8)
    const int t = threadIdx.x;
    const int l = t & 31, g = t >> 5;            // g: 0..15 s-phase
    __shared__ float al[2048];
    __shared__ f32x4 part[16][33];
    for (int j = t; j < 2048; j += 512) al[j] = alpha[b * 2048 + j];
    __syncthreads();
    const float4* ep = (const float4*)enc + ((size_t)b * 2048 + g) * 256 + ec * 32 + l;
    f32x4 acc = (f32x4){0.f, 0.f, 0.f, 0.f};
#pragma unroll 8
    for (int it = 0; it < 128; ++it) {           // s = g + it*16
        float4 v = ep[(size_t)it * 4096];
        float a = al[g + it * 16];
        acc.x += a * v.x;
        acc.y += a * v.y;
        acc.z += a * v.z;
        acc.w += a * v.w;
    }
    part[g][l] = acc;
    __syncthreads();
    if (t < 32) {
        f32x4 s = part[0][t];
#pragma unroll
        for (int gg = 1; gg < 16; ++gg) {
            f32x4 p = part[gg][t];
            s.x += p.x; s.y += p.y; s.z += p.z; s.w += p.w;
        }
        *(float4*)(out + (size_t)b * 1024 + ec * 128 + t * 4) =
            (float4){s.x, s.y, s.z, s.w};
    }
}

// ---------- launch ----------

extern "C" void kernel_launch(void* const* d_in, const int* in_sizes, int n_in,
                              void* d_out, int out_size, void* d_ws, size_t ws_size,
                              hipStream_t stream) {
    const float* enc  = (const float*)d_in[0];
    const float* dh   = (const float*)d_in[1];
    const float* Wenc = (const float*)d_in[2];
    const float* benc = (const float*)d_in[3];
    const float* Wdec = (const float*)d_in[4];
    const float* bdec = (const float*)d_in[5];
    const float* Wv   = (const float*)d_in[6];
    // b_v is a constant shift on scores -> softmax-invariant, ignored.
    float* out = (float*)d_out;                 // [32*1024 context | 32*2048 alpha]

    char* ws = (char*)d_ws;
    ushort_t* wencB = (ushort_t*)ws;                          // 2 MiB
    float* dproj    = (float*)(ws + 2097152ull);              // 128 KiB
    float* scores   = (float*)(ws + 2097152ull + 131072ull);  // 256 KiB

    k_prep<<<8448, 256, 0, stream>>>(Wenc, dh, Wdec, bdec, benc,
                                     wencB, dproj, (float4*)scores);
    k_gemm_scores<<<2048, 256, 0, stream>>>(enc, wencB, dproj, Wv, scores);
    k_softmax<<<32, 256, 0, stream>>>(scores, out + 32768);
    k_context<<<dim3(32, 8), 512, 0, stream>>>(enc, out + 32768, out);
}

// Round 2
// 592.633 us; speedup vs baseline: 1.0267x; 1.0267x over previous
//
#include <hip/hip_runtime.h>

typedef unsigned short ushort_t;
typedef __attribute__((ext_vector_type(8))) short short8;
typedef __attribute__((ext_vector_type(4))) float f32x4;
typedef __attribute__((ext_vector_type(4))) unsigned int u32x4;

// ---------- helpers ----------

__device__ __forceinline__ ushort_t f2bf(float f) {
    unsigned u = __builtin_bit_cast(unsigned, f);
    u += 0x7fffu + ((u >> 16) & 1u);   // round-to-nearest-even
    return (ushort_t)(u >> 16);
}

// packed fp32x2 -> bf16x2 (RNE), low half = a
__device__ __forceinline__ unsigned pkbf(float a, float b) {
    unsigned r;
    asm("v_cvt_pk_bf16_f32 %0, %1, %2" : "=v"(r) : "v"(a), "v"(b));
    return r;
}

__device__ __forceinline__ float tanh_fast(float x) {
    float e = __expf(2.0f * x);
    float r = __builtin_amdgcn_rcpf(e + 1.0f);
    return __builtin_fmaf(-2.0f, r, 1.0f);
}

__device__ __forceinline__ void gld16(const ushort_t* g, ushort_t* lds) {
    __builtin_amdgcn_global_load_lds(
        (const __attribute__((address_space(1))) unsigned int*)g,
        (__attribute__((address_space(3))) unsigned int*)lds, 16, 0, 0);
}

// ---------- K_prep: Wenc fp32->bf16 + zero scores (blocks 0..255)
//                    dproj = dh@Wdec^T + bdec + benc  (blocks 256..8447)

__global__ __launch_bounds__(256) void k_prep(const float* __restrict__ Wenc,
                                              const float* __restrict__ dh,
                                              const float* __restrict__ Wd,
                                              const float* __restrict__ bd,
                                              const float* __restrict__ be,
                                              ushort_t* __restrict__ wencB,
                                              float* __restrict__ dproj,
                                              float4* __restrict__ scores4) {
    const int bx = blockIdx.x;
    const int t = threadIdx.x;
    if (bx < 256) {
        int idx = bx * 256 + t;                      // 0..65535
#pragma unroll
        for (int r = 0; r < 4; ++r) {                // 262144 float4 of Wenc
            int i = idx + r * 65536;
            float4 v = ((const float4*)Wenc)[i];
            ushort4 o;
            o.x = f2bf(v.x); o.y = f2bf(v.y); o.z = f2bf(v.z); o.w = f2bf(v.w);
            ((ushort4*)wencB)[i] = o;
        }
        if (idx < 16384) scores4[idx] = (float4){0.f, 0.f, 0.f, 0.f};
    } else {
        int wid = (bx - 256) * 4 + (t >> 6);         // 0..32767
        int lane = t & 63;
        int a = wid & 1023, b = wid >> 10;
        const float4* x = (const float4*)(dh + (size_t)b * 1024);
        const float4* wrow = (const float4*)(Wd + (size_t)a * 1024);
        float s = 0.f;
#pragma unroll
        for (int it = 0; it < 4; ++it) {
            int c = it * 64 + lane;
            float4 xv = x[c], wv = wrow[c];
            s += xv.x * wv.x + xv.y * wv.y + xv.z * wv.z + xv.w * wv.w;
        }
#pragma unroll
        for (int o = 1; o < 64; o <<= 1) s += __shfl_xor(s, o, 64);
        if (lane == 0) dproj[b * 1024 + a] = s + bd[a] + be[a];
    }
}

// ---------- K2: fused cvt + GEMM + tanh + W_v reduction -> scores ----------
// T14 schedule: A fp32 loads for tile t+1 issued BEFORE compute of tile t
// (latency hidden under 128 MFMAs); cvt+ds_write after the post-compute
// barrier. B double-buffered in LDS so its DMA also issues before compute.
// MFMA core / swizzled LDS mapping identical to the verified kernel.

__global__ __launch_bounds__(256, 2) void k_gemm_scores(const float* __restrict__ A,
                                                        const ushort_t* __restrict__ Bm,
                                                        const float* __restrict__ dproj,
                                                        const float* __restrict__ Wv,
                                                        float* __restrict__ scores) {
    __shared__ __align__(16) ushort_t At[256 * 64];      // 32 KB
    __shared__ __align__(16) ushort_t Bt[2][128 * 64];   // 32 KB (double-buffered)

    const int tid = threadIdx.x;
    const int lane = tid & 63;
    const int w = tid >> 6;            // wave 0..3
    const int wm = w >> 1, wn = w & 1; // waves: 2 (M) x 2 (N); wave tile 128x64

    // XCD swizzle: blk&7 ~ XCD; the 8 N-sharers of an A-tile land on one XCD
    const int blk = blockIdx.x;        // 0..2047
    const int q2 = blk >> 3;           // 0..255
    const int blkN = q2 & 7;           // 0..7
    const int blkM = (blk & 7) + ((q2 >> 3) << 3);  // 0..255
    const long long arow0 = (long long)blkM * 256;
    const int brow0 = blkN * 128;

    const int sr = lane >> 3;          // row within 8-row staging chunk
    const int sgrp = lane & 7;         // 16B slot within row
    const int c8s = sgrp ^ sr;         // XOR-swizzled col-group

    const int q = lane >> 4;           // quad
    const int ml = lane & 15;

    // A: linear fp32 source; each lane owns 8 consecutive floats (2 float4)
    const float4* ga = (const float4*)(A + (size_t)(arow0 + w * 64 + sr) * 1024) + sgrp * 2;
    // B: pre-swizzled bf16 source for linear global_load_lds destination
    const ushort_t* gb = Bm + (size_t)(brow0 + w * 32 + sr) * 1024 + c8s * 8;
    // A LDS write address: XOR swizzle applied on the write side
    ushort_t* atw = &At[w * 8 * 512 + sr * 64 + (c8s << 3)];   // chunk j at +j*512

    f32x4 acc[8][4];
#pragma unroll
    for (int i = 0; i < 8; ++i)
#pragma unroll
        for (int jj = 0; jj < 4; ++jj) acc[i][jj] = (f32x4){0.f, 0.f, 0.f, 0.f};

    float4 p[16];

    // ---- prologue: tile 0 ----
#pragma unroll
    for (int j = 0; j < 8; ++j) { p[2 * j] = ga[j * 2048]; p[2 * j + 1] = ga[j * 2048 + 1]; }
#pragma unroll
    for (int j = 0; j < 4; ++j) gld16(gb + j * 8192, &Bt[0][(w * 4 + j) * 512]);
    ga += 16; gb += 64;
#pragma unroll
    for (int j = 0; j < 8; ++j) {
        u32x4 o;
        o.x = pkbf(p[2 * j].x, p[2 * j].y);         o.y = pkbf(p[2 * j].z, p[2 * j].w);
        o.z = pkbf(p[2 * j + 1].x, p[2 * j + 1].y); o.w = pkbf(p[2 * j + 1].z, p[2 * j + 1].w);
        *(u32x4*)(atw + j * 512) = o;
    }
    __syncthreads();   // drains vmcnt (B DMA) + lgkm (A writes)

    for (int k0 = 0; k0 < 1024; k0 += 64) {
        const int cur = (k0 >> 6) & 1;
        const bool more = k0 < 960;
        if (more) {
            // issue-early: next tile's A loads + B DMA, hidden under compute
#pragma unroll
            for (int j = 0; j < 8; ++j) { p[2 * j] = ga[j * 2048]; p[2 * j + 1] = ga[j * 2048 + 1]; }
#pragma unroll
            for (int j = 0; j < 4; ++j) gld16(gb + j * 8192, &Bt[cur ^ 1][(w * 4 + j) * 512]);
            ga += 16; gb += 64;
        }
        // ---- compute tile t from At / Bt[cur] ----
#pragma unroll
        for (int kk = 0; kk < 2; ++kk) {
            const int kb = kk * 4;
            const int slot = (kb + q) ^ (ml & 7);     // same for A and B frags
            short8 bfr[4];
#pragma unroll
            for (int jj = 0; jj < 4; ++jj) {
                int col = wn * 64 + jj * 16 + ml;
                bfr[jj] = *(const short8*)&Bt[cur][col * 64 + slot * 8];
            }
#pragma unroll
            for (int i = 0; i < 8; ++i) {
                int row = wm * 128 + i * 16 + ml;
                short8 af = *(const short8*)&At[row * 64 + slot * 8];
#pragma unroll
                for (int jj = 0; jj < 4; ++jj)
                    acc[i][jj] = __builtin_amdgcn_mfma_f32_16x16x32_bf16(
                        af, bfr[jj], acc[i][jj], 0, 0, 0);
            }
        }
        __syncthreads();          // all At reads done (drains vmcnt: p + B ready)
        if (more) {
            // write-late: cvt + swizzled ds_write of the prefetched A tile
#pragma unroll
            for (int j = 0; j < 8; ++j) {
                u32x4 o;
                o.x = pkbf(p[2 * j].x, p[2 * j].y);         o.y = pkbf(p[2 * j].z, p[2 * j].w);
                o.z = pkbf(p[2 * j + 1].x, p[2 * j + 1].y); o.w = pkbf(p[2 * j + 1].z, p[2 * j + 1].w);
                *(u32x4*)(atw + j * 512) = o;
            }
        }
        __syncthreads();          // At writes visible
    }

    // epilogue: scores[m] += sum_a Wv[a]*tanh(acc + dproj[b,a]) over 128 cols
    const int bb = blkM >> 3;  // 8 M-blocks (256 rows) per batch (2048 rows)
    float dp[4], wv[4];
#pragma unroll
    for (int jj = 0; jj < 4; ++jj) {
        int a = blkN * 128 + wn * 64 + jj * 16 + ml;
        dp[jj] = dproj[bb * 1024 + a];
        wv[jj] = Wv[a];
    }
#pragma unroll
    for (int i = 0; i < 8; ++i) {
        float rs[4] = {0.f, 0.f, 0.f, 0.f};
#pragma unroll
        for (int jj = 0; jj < 4; ++jj) {
            f32x4 v = acc[i][jj];
            rs[0] += wv[jj] * tanh_fast(v.x + dp[jj]);
            rs[1] += wv[jj] * tanh_fast(v.y + dp[jj]);
            rs[2] += wv[jj] * tanh_fast(v.z + dp[jj]);
            rs[3] += wv[jj] * tanh_fast(v.w + dp[jj]);
        }
#pragma unroll
        for (int r = 0; r < 4; ++r)
#pragma unroll
            for (int o = 1; o < 16; o <<= 1) rs[r] += __shfl_xor(rs[r], o, 64);
        if (ml == 0) {
            long long m0 = arow0 + wm * 128 + i * 16 + q * 4;
            atomicAdd(&scores[m0 + 0], rs[0]);
            atomicAdd(&scores[m0 + 1], rs[1]);
            atomicAdd(&scores[m0 + 2], rs[2]);
            atomicAdd(&scores[m0 + 3], rs[3]);
        }
    }
}

// ---------- K3: fused softmax + context ----------
// grid (32, 8), 512 threads. Each block redoes the (trivial) 2048-wide softmax
// for its batch row in LDS, then computes a 128-col slice of context.
// ec==0 blocks also write alpha. Saves a kernel launch + alpha round-trip.

__global__ __launch_bounds__(512) void k_ctx(const float* __restrict__ enc,
                                             const float* __restrict__ scores,
                                             float* __restrict__ out) {
    const int b = blockIdx.x, ec = blockIdx.y;   // (32, 8)
    const int t = threadIdx.x;
    const int l = t & 31, g = t >> 5;            // g: 0..15 s-phase
    const int lane = t & 63, wv = t >> 6;        // 8 waves
    __shared__ float al[2048];
    __shared__ float red[8];
    __shared__ f32x4 part[16][33];

    // softmax over scores[b, 0..2047]; each thread owns 4 consecutive values
    float4 v = ((const float4*)scores)[b * 512 + t];
    float mx = fmaxf(fmaxf(v.x, v.y), fmaxf(v.z, v.w));
#pragma unroll
    for (int o = 1; o < 64; o <<= 1) mx = fmaxf(mx, __shfl_xor(mx, o, 64));
    if (lane == 0) red[wv] = mx;
    __syncthreads();
    mx = red[0];
#pragma unroll
    for (int j = 1; j < 8; ++j) mx = fmaxf(mx, red[j]);
    float e0 = __expf(v.x - mx), e1 = __expf(v.y - mx);
    float e2 = __expf(v.z - mx), e3 = __expf(v.w - mx);
    float s = e0 + e1 + e2 + e3;
#pragma unroll
    for (int o = 1; o < 64; o <<= 1) s += __shfl_xor(s, o, 64);
    __syncthreads();
    if (lane == 0) red[wv] = s;
    __syncthreads();
    s = 0.f;
#pragma unroll
    for (int j = 0; j < 8; ++j) s += red[j];
    float inv = 1.0f / s;
    float4 a4 = (float4){e0 * inv, e1 * inv, e2 * inv, e3 * inv};
    ((float4*)al)[t] = a4;
    if (ec == 0) ((float4*)(out + 32768 + (size_t)b * 2048))[t] = a4;
    __syncthreads();

    // context[b, ec*128 .. ec*128+127] = sum_s alpha[s] * enc[b, s, :]
    const float4* ep = (const float4*)enc + ((size_t)b * 2048 + g) * 256 + ec * 32 + l;
    f32x4 acc = (f32x4){0.f, 0.f, 0.f, 0.f};
#pragma unroll 8
    for (int it = 0; it < 128; ++it) {           // s = g + it*16
        float4 vv = ep[(size_t)it * 4096];
        float a = al[g + it * 16];
        acc.x += a * vv.x;
        acc.y += a * vv.y;
        acc.z += a * vv.z;
        acc.w += a * vv.w;
    }
    part[g][l] = acc;
    __syncthreads();
    if (t < 32) {
        f32x4 ss = part[0][t];
#pragma unroll
        for (int gg = 1; gg < 16; ++gg) {
            f32x4 pp = part[gg][t];
            ss.x += pp.x; ss.y += pp.y; ss.z += pp.z; ss.w += pp.w;
        }
        *(float4*)(out + (size_t)b * 1024 + ec * 128 + t * 4) =
            (float4){ss.x, ss.y, ss.z, ss.w};
    }
}

// ---------- launch ----------

extern "C" void kernel_launch(void* const* d_in, const int* in_sizes, int n_in,
                              void* d_out, int out_size, void* d_ws, size_t ws_size,
                              hipStream_t stream) {
    const float* enc  = (const float*)d_in[0];
    const float* dh   = (const float*)d_in[1];
    const float* Wenc = (const float*)d_in[2];
    const float* benc = (const float*)d_in[3];
    const float* Wdec = (const float*)d_in[4];
    const float* bdec = (const float*)d_in[5];
    const float* Wv   = (const float*)d_in[6];
    // b_v is a constant shift on scores -> softmax-invariant, ignored.
    float* out = (float*)d_out;                 // [32*1024 context | 32*2048 alpha]

    char* ws = (char*)d_ws;
    ushort_t* wencB = (ushort_t*)ws;                          // 2 MiB
    float* dproj    = (float*)(ws + 2097152ull);              // 128 KiB
    float* scores   = (float*)(ws + 2097152ull + 131072ull);  // 256 KiB

    k_prep<<<8448, 256, 0, stream>>>(Wenc, dh, Wdec, bdec, benc,
                                     wencB, dproj, (float4*)scores);
    k_gemm_scores<<<2048, 256, 0, stream>>>(enc, wencB, dproj, Wv, scores);
    k_ctx<<<dim3(32, 8), 512, 0, stream>>>(enc, scores, out);
}

// Round 3
// 545.931 us; speedup vs baseline: 1.1145x; 1.0855x over previous
//
#include <hip/hip_runtime.h>

typedef unsigned short ushort_t;
typedef __attribute__((ext_vector_type(8))) short short8;
typedef __attribute__((ext_vector_type(4))) float f32x4;

// ---------- helpers ----------

__device__ __forceinline__ ushort_t f2bf(float f) {
    unsigned u = __builtin_bit_cast(unsigned, f);
    u += 0x7fffu + ((u >> 16) & 1u);   // round-to-nearest-even
    return (ushort_t)(u >> 16);
}

__device__ __forceinline__ float bf2f(ushort_t h) {
    unsigned u = ((unsigned)h) << 16;
    return __builtin_bit_cast(float, u);
}

__device__ __forceinline__ float tanh_fast(float x) {
    float e = __expf(2.0f * x);
    float r = __builtin_amdgcn_rcpf(e + 1.0f);
    return __builtin_fmaf(-2.0f, r, 1.0f);
}

__device__ __forceinline__ void gld16(const ushort_t* g, ushort_t* lds) {
    __builtin_amdgcn_global_load_lds(
        (const __attribute__((address_space(1))) unsigned int*)g,
        (__attribute__((address_space(3))) unsigned int*)lds, 16, 0, 0);
}

// ---------- K_front: enc/Wenc fp32->bf16 + zero scores (blocks 0..8191)
//                     dproj = dh@Wdec^T + bdec + benc      (blocks 8192..16383)

__global__ __launch_bounds__(256) void k_front(const float* __restrict__ enc,
                                               const float* __restrict__ Wenc,
                                               const float* __restrict__ dh,
                                               const float* __restrict__ Wd,
                                               const float* __restrict__ bd,
                                               const float* __restrict__ be,
                                               ushort_t* __restrict__ encB,
                                               ushort_t* __restrict__ wencB,
                                               float* __restrict__ dproj,
                                               float4* __restrict__ scores4) {
    const int bx = blockIdx.x;
    const int t = threadIdx.x;
    if (bx < 8192) {
        int i = bx * 256 + t;
        for (; i < 17055744; i += 2097152) {
            if (i < 16777216) {                       // enc: 16.7M float4
                float4 v = ((const float4*)enc)[i];
                ushort4 o;
                o.x = f2bf(v.x); o.y = f2bf(v.y); o.z = f2bf(v.z); o.w = f2bf(v.w);
                ((ushort4*)encB)[i] = o;
            } else if (i < 17039360) {                // Wenc: 262144 float4
                int j = i - 16777216;
                float4 v = ((const float4*)Wenc)[j];
                ushort4 o;
                o.x = f2bf(v.x); o.y = f2bf(v.y); o.z = f2bf(v.z); o.w = f2bf(v.w);
                ((ushort4*)wencB)[j] = o;
            } else {                                  // scores zeros
                scores4[i - 17039360] = (float4){0.f, 0.f, 0.f, 0.f};
            }
        }
    } else {
        int wid = (bx - 8192) * 4 + (t >> 6);
        int lane = t & 63;
        int a = wid & 1023, b = wid >> 10;
        const float4* x = (const float4*)(dh + (size_t)b * 1024);
        const float4* wrow = (const float4*)(Wd + (size_t)a * 1024);
        float s = 0.f;
#pragma unroll
        for (int it = 0; it < 4; ++it) {
            int c = it * 64 + lane;
            float4 xv = x[c], wv = wrow[c];
            s += xv.x * wv.x + xv.y * wv.y + xv.z * wv.z + xv.w * wv.w;
        }
#pragma unroll
        for (int o = 1; o < 64; o <<= 1) s += __shfl_xor(s, o, 64);
        if (lane == 0) dproj[b * 1024 + a] = s + bd[a] + be[a];
    }
}

// ---------- K2: fused GEMM + tanh + W_v reduction -> scores ----------
// Verbatim round-0 kernel (measured 172 us, MfmaUtil 34%): 256x128 block tile
// (4 waves, 128x64 each), BK=64, single-buffer 48 KB LDS, 16x16x32 bf16 MFMA,
// global_load_lds(16) for BOTH A and B, XOR-swizzled LDS, XCD-aware grid.

__global__ __launch_bounds__(256, 2) void k_gemm_scores(const ushort_t* __restrict__ A,
                                                        const ushort_t* __restrict__ Bm,
                                                        const float* __restrict__ dproj,
                                                        const float* __restrict__ Wv,
                                                        float* __restrict__ scores) {
    __shared__ __align__(16) ushort_t At[256 * 64];  // 32 KB
    __shared__ __align__(16) ushort_t Bt[128 * 64];  // 16 KB

    const int tid = threadIdx.x;
    const int lane = tid & 63;
    const int w = tid >> 6;            // wave 0..3
    const int wm = w >> 1, wn = w & 1; // waves: 2 (M) x 2 (N); wave tile 128x64

    // XCD swizzle: blk&7 ~ XCD; the 8 N-sharers of an A-tile land on one XCD
    const int blk = blockIdx.x;        // 0..2047
    const int q2 = blk >> 3;           // 0..255
    const int blkN = q2 & 7;           // 0..7
    const int blkM = (blk & 7) + ((q2 >> 3) << 3);  // 0..255
    const long long arow0 = (long long)blkM * 256;
    const int brow0 = blkN * 128;

    const int sr = lane >> 3;          // row within 8-row staging group
    const int sgrp = lane & 7;         // 16B slot within row
    const int c8s = sgrp ^ sr;         // XOR-swizzled source column-group

    const int q = lane >> 4;           // quad
    const int ml = lane & 15;

    const ushort_t* ga = A + (arow0 + w * 64 + sr) * 1024 + c8s * 8;
    const ushort_t* gb = Bm + (long long)(brow0 + w * 32 + sr) * 1024 + c8s * 8;

    f32x4 acc[8][4];
#pragma unroll
    for (int i = 0; i < 8; ++i)
#pragma unroll
        for (int jj = 0; jj < 4; ++jj) acc[i][jj] = (f32x4){0.f, 0.f, 0.f, 0.f};

    for (int k0 = 0; k0 < 1024; k0 += 64) {
        __syncthreads();   // previous compute done before overwriting LDS
#pragma unroll
        for (int j = 0; j < 8; ++j)                   // A: 64 rows per wave
            gld16(ga + j * 8192, &At[(w * 8 + j) * 512]);
#pragma unroll
        for (int j = 0; j < 4; ++j)                   // B: 32 rows per wave
            gld16(gb + j * 8192, &Bt[(w * 4 + j) * 512]);
        ga += 64; gb += 64;
        __builtin_amdgcn_s_waitcnt(0);  // drain vmcnt before barrier
        __syncthreads();

#pragma unroll
        for (int kk = 0; kk < 2; ++kk) {  // two k-steps of 32
            const int kb = kk * 4;
            const int slot = (kb + q) ^ (ml & 7);     // same for A and B frags
            short8 af[8], bfr[4];
#pragma unroll
            for (int i = 0; i < 8; ++i) {
                int row = wm * 128 + i * 16 + ml;
                af[i] = *(const short8*)&At[row * 64 + slot * 8];
            }
#pragma unroll
            for (int jj = 0; jj < 4; ++jj) {
                int col = wn * 64 + jj * 16 + ml;
                bfr[jj] = *(const short8*)&Bt[col * 64 + slot * 8];
            }
#pragma unroll
            for (int i = 0; i < 8; ++i)
#pragma unroll
                for (int jj = 0; jj < 4; ++jj)
                    acc[i][jj] = __builtin_amdgcn_mfma_f32_16x16x32_bf16(
                        af[i], bfr[jj], acc[i][jj], 0, 0, 0);
        }
    }

    // epilogue: scores[m] += sum_a Wv[a]*tanh(acc + dproj[b,a]) over 128 cols
    const int bb = blkM >> 3;  // 8 M-blocks (256 rows) per batch (2048 rows)
    float dp[4], wv[4];
#pragma unroll
    for (int jj = 0; jj < 4; ++jj) {
        int a = blkN * 128 + wn * 64 + jj * 16 + ml;
        dp[jj] = dproj[bb * 1024 + a];
        wv[jj] = Wv[a];
    }
#pragma unroll
    for (int i = 0; i < 8; ++i) {
        float rs[4] = {0.f, 0.f, 0.f, 0.f};
#pragma unroll
        for (int jj = 0; jj < 4; ++jj) {
            f32x4 v = acc[i][jj];
            rs[0] += wv[jj] * tanh_fast(v.x + dp[jj]);
            rs[1] += wv[jj] * tanh_fast(v.y + dp[jj]);
            rs[2] += wv[jj] * tanh_fast(v.z + dp[jj]);
            rs[3] += wv[jj] * tanh_fast(v.w + dp[jj]);
        }
#pragma unroll
        for (int r = 0; r < 4; ++r)
#pragma unroll
            for (int o = 1; o < 16; o <<= 1) rs[r] += __shfl_xor(rs[r], o, 64);
        if (ml == 0) {
            long long m0 = arow0 + wm * 128 + i * 16 + q * 4;
            atomicAdd(&scores[m0 + 0], rs[0]);
            atomicAdd(&scores[m0 + 1], rs[1]);
            atomicAdd(&scores[m0 + 2], rs[2]);
            atomicAdd(&scores[m0 + 3], rs[3]);
        }
    }
}

// ---------- K3: fused softmax + context (reads bf16 encB, direct stores) ----
// grid (32, 8), 512 threads. Each block redoes the cheap 2048-wide softmax
// for its batch row in LDS, then computes a 128-col slice of context from the
// materialized bf16 encB (half the bytes of fp32 enc). ec==0 writes alpha.

__global__ __launch_bounds__(512) void k_ctx(const ushort_t* __restrict__ encB,
                                             const float* __restrict__ scores,
                                             float* __restrict__ out) {
    const int b = blockIdx.x, ec = blockIdx.y;   // (32, 8)
    const int t = threadIdx.x;
    const int l = t & 31, g = t >> 5;            // g: 0..15 s-phase
    const int lane = t & 63, wv = t >> 6;        // 8 waves
    __shared__ float al[2048];
    __shared__ float red[8];
    __shared__ f32x4 part[16][33];

    // softmax over scores[b, 0..2047]; each thread owns 4 consecutive values
    float4 v = ((const float4*)scores)[b * 512 + t];
    float mx = fmaxf(fmaxf(v.x, v.y), fmaxf(v.z, v.w));
#pragma unroll
    for (int o = 1; o < 64; o <<= 1) mx = fmaxf(mx, __shfl_xor(mx, o, 64));
    if (lane == 0) red[wv] = mx;
    __syncthreads();
    mx = red[0];
#pragma unroll
    for (int j = 1; j < 8; ++j) mx = fmaxf(mx, red[j]);
    float e0 = __expf(v.x - mx), e1 = __expf(v.y - mx);
    float e2 = __expf(v.z - mx), e3 = __expf(v.w - mx);
    float s = e0 + e1 + e2 + e3;
#pragma unroll
    for (int o = 1; o < 64; o <<= 1) s += __shfl_xor(s, o, 64);
    __syncthreads();
    if (lane == 0) red[wv] = s;
    __syncthreads();
    s = 0.f;
#pragma unroll
    for (int j = 0; j < 8; ++j) s += red[j];
    float inv = 1.0f / s;
    float4 a4 = (float4){e0 * inv, e1 * inv, e2 * inv, e3 * inv};
    ((float4*)al)[t] = a4;
    if (ec == 0) ((float4*)(out + 32768 + (size_t)b * 2048))[t] = a4;
    __syncthreads();

    // context[b, ec*128 .. +128) = sum_s alpha[s] * encB[b, s, :]
    const ushort_t* ep = encB + ((size_t)b * 2048 + g) * 1024 + ec * 128 + l * 4;
    f32x4 acc = (f32x4){0.f, 0.f, 0.f, 0.f};
#pragma unroll 8
    for (int it = 0; it < 128; ++it) {           // s = g + it*16
        ushort4 ev = *(const ushort4*)(ep + (size_t)it * 16384);
        float a = al[g + it * 16];
        acc.x += a * bf2f(ev.x);
        acc.y += a * bf2f(ev.y);
        acc.z += a * bf2f(ev.z);
        acc.w += a * bf2f(ev.w);
    }
    part[g][l] = acc;
    __syncthreads();
    if (t < 32) {
        f32x4 ss = part[0][t];
#pragma unroll
        for (int gg = 1; gg < 16; ++gg) {
            f32x4 pp = part[gg][t];
            ss.x += pp.x; ss.y += pp.y; ss.z += pp.z; ss.w += pp.w;
        }
        *(float4*)(out + (size_t)b * 1024 + ec * 128 + t * 4) =
            (float4){ss.x, ss.y, ss.z, ss.w};
    }
}

// ---------- launch ----------

extern "C" void kernel_launch(void* const* d_in, const int* in_sizes, int n_in,
                              void* d_out, int out_size, void* d_ws, size_t ws_size,
                              hipStream_t stream) {
    const float* enc  = (const float*)d_in[0];
    const float* dh   = (const float*)d_in[1];
    const float* Wenc = (const float*)d_in[2];
    const float* benc = (const float*)d_in[3];
    const float* Wdec = (const float*)d_in[4];
    const float* bdec = (const float*)d_in[5];
    const float* Wv   = (const float*)d_in[6];
    // b_v is a constant shift on scores -> softmax-invariant, ignored.
    float* out = (float*)d_out;                 // [32*1024 context | 32*2048 alpha]

    char* ws = (char*)d_ws;
    ushort_t* encB  = (ushort_t*)ws;                              // 128 MiB
    ushort_t* wencB = (ushort_t*)(ws + 134217728ull);             // 2 MiB
    float* dproj    = (float*)(ws + 134217728ull + 2097152ull);   // 128 KiB
    float* scores   = (float*)(ws + 134217728ull + 2097152ull + 131072ull); // 256 KiB

    k_front<<<16384, 256, 0, stream>>>(enc, Wenc, dh, Wdec, bdec, benc,
                                       encB, wencB, dproj, (float4*)scores);
    k_gemm_scores<<<2048, 256, 0, stream>>>(encB, wencB, dproj, Wv, scores);
    k_ctx<<<dim3(32, 8), 512, 0, stream>>>(encB, scores, out);
}